// Round 5
// baseline (233.198 us; speedup 1.0000x reference)
//
#include <hip/hip_runtime.h>
#include <math.h>

// Problem constants (MoEGate: B=4,T=4096,C=2048,E=64,K=8)
#define NTOK   16384
#define CDIM   2048
#define NEXP   64
#define TOPK   8
#define KSPLIT 4
#define RBLK   1024          // reduce_topk grid (16 tokens per block)

typedef _Float16 f16x8 __attribute__((ext_vector_type(8)));
typedef float    f32x4 __attribute__((ext_vector_type(4)));

// ============================================================================
// Kernel 1: pack W[64][2048] fp32 into f16 hi/lo images in MFMA B-fragment
// order. Entry t = ((s*4 + nt)*64 + lane): 8 f16 for (expert = nt*16+(lane&15),
// k = s*32 + (lane>>4)*8 + j). GEMM lane then loads one contiguous 16B chunk.
// ============================================================================
__global__ __launch_bounds__(256) void pack_w16_kernel(
    const float* __restrict__ W,
    _Float16* __restrict__ Wh, _Float16* __restrict__ Wl)
{
    int t    = blockIdx.x * 256 + threadIdx.x;   // 0..16383
    int lane = t & 63;
    int nt   = (t >> 6) & 3;
    int s    = t >> 8;                           // k32-step, 0..63
    int e    = nt * 16 + (lane & 15);
    int k    = s * 32 + (lane >> 4) * 8;
    const float* src = W + (size_t)e * CDIM + k;
    #pragma unroll
    for (int j = 0; j < 8; j++) {
        float x = src[j];
        _Float16 h = (_Float16)x;                // rte
        Wh[(size_t)t * 8 + j] = h;
        Wl[(size_t)t * 8 + j] = (_Float16)(x - (float)h);
    }
}

// ============================================================================
// Kernel 2: f16-split MFMA GEMM (unchanged from R4 — measured ~35 us).
// Wave = 16 tokens x 64 experts over a k-slice of 512 (KSPLIT=4). A-frags
// loaded directly from global, split to f16 hi/lo in-register; B-frags from
// packed images (L2-hot). 3 MFMAs per (k32, n-tile): hh + lh + hl.
// No LDS, no barriers. fp32 partials to part[pp][tok][e].
// ============================================================================
__global__ __launch_bounds__(256, 4) void gemm_f16split_kernel(
    const float* __restrict__ x,       // [NTOK][CDIM]
    const _Float16* __restrict__ Wh,   // packed image, 256 KB
    const _Float16* __restrict__ Wl,   // packed image, 256 KB
    float* __restrict__ part)          // [KSPLIT][NTOK][NEXP]
{
    const int lane = threadIdx.x & 63;
    const int wid  = threadIdx.x >> 6;
    const int tb   = blockIdx.x & 255;           // token block (64 tokens)
    const int pp   = blockIdx.x >> 8;            // k-split part
    const int tok0 = tb * 64 + wid * 16;
    const int q    = lane >> 4;                  // quad
    const size_t xbase = (size_t)(tok0 + (lane & 15)) * CDIM + pp * 512 + q * 8;

    f32x4 acc[4];
    #pragma unroll
    for (int nt = 0; nt < 4; nt++) acc[nt] = (f32x4){0.f, 0.f, 0.f, 0.f};

    for (int s = 0; s < 16; s++) {
        const int S = pp * 16 + s;               // absolute k32-step
        float4 v0 = *(const float4*)&x[xbase + s * 32];
        float4 v1 = *(const float4*)&x[xbase + s * 32 + 4];
        float xr[8] = {v0.x, v0.y, v0.z, v0.w, v1.x, v1.y, v1.z, v1.w};
        f16x8 ah, al;
        #pragma unroll
        for (int j = 0; j < 8; j++) {
            _Float16 h = (_Float16)xr[j];
            ah[j] = h;
            al[j] = (_Float16)(xr[j] - (float)h);
        }
        const f16x8* bhp = (const f16x8*)(Wh + ((size_t)S * 4 * 64 + lane) * 8);
        const f16x8* blp = (const f16x8*)(Wl + ((size_t)S * 4 * 64 + lane) * 8);
        #pragma unroll
        for (int nt = 0; nt < 4; nt++) {
            f16x8 bh = bhp[nt * 64];
            f16x8 bl = blp[nt * 64];
            acc[nt] = __builtin_amdgcn_mfma_f32_16x16x32_f16(ah, bh, acc[nt], 0, 0, 0);
            acc[nt] = __builtin_amdgcn_mfma_f32_16x16x32_f16(al, bh, acc[nt], 0, 0, 0);
            acc[nt] = __builtin_amdgcn_mfma_f32_16x16x32_f16(ah, bl, acc[nt], 0, 0, 0);
        }
    }

    // D layout: token = tok0 + q*4 + r, expert = nt*16 + (lane&15)
    #pragma unroll
    for (int nt = 0; nt < 4; nt++) {
        #pragma unroll
        for (int r = 0; r < 4; r++) {
            size_t tok = (size_t)tok0 + q * 4 + r;
            part[((size_t)pp * NTOK + tok) * NEXP + nt * 16 + (lane & 15)] = acc[nt][r];
        }
    }
}

// ============================================================================
// Kernel 3 (REWRITTEN): coalesced reduce + parallel top-8.
// Grid 1024 x 256 threads; block = 16 tokens x 16 lanes/token.
// Thread (tok, l) owns experts 4l..4l+3 in registers: the k-split sum is 4
// coalesced float4 loads (wave reads contiguous 1 KB per partial). Top-8 via
// 16-lane shfl_xor argmax (strict >, lowest index wins ties = JAX). Counts:
// LDS atomics -> blockcnt[1024][64]; ZERO global atomics.
// ============================================================================
__global__ __launch_bounds__(256) void reduce_topk_kernel(
    const float* __restrict__ part,     // [KSPLIT][NTOK][NEXP]
    const int*   __restrict__ mask,     // [NTOK]
    const float* __restrict__ gbias,    // [NEXP]
    const float* __restrict__ ebias,    // [NEXP]
    float*       __restrict__ out,      // [2*NTOK*TOPK + 1]
    float*       __restrict__ blockcnt) // [RBLK][NEXP]
{
    __shared__ unsigned int cnt[NEXP];
    const int tid = threadIdx.x;
    if (tid < NEXP) cnt[tid] = 0u;
    __syncthreads();

    const int t = blockIdx.x * 16 + (tid >> 4);  // token
    const int l = tid & 15;                      // lane within token group

    // sum k-split partials: this thread owns experts 4l..4l+3
    float4 v = make_float4(0.f, 0.f, 0.f, 0.f);
    #pragma unroll
    for (int p = 0; p < KSPLIT; p++) {
        float4 u = *(const float4*)&part[((size_t)p * NTOK + t) * NEXP + l * 4];
        v.x += u.x; v.y += u.y; v.z += u.z; v.w += u.w;
    }
    float4 gb = *(const float4*)&gbias[l * 4];
    float4 eb = *(const float4*)&ebias[l * 4];
    float z[4], sel[4];
    z[0] = v.x + gb.x; z[1] = v.y + gb.y; z[2] = v.z + gb.z; z[3] = v.w + gb.w;
    sel[0] = z[0] + eb.x; sel[1] = z[1] + eb.y;
    sel[2] = z[2] + eb.z; sel[3] = z[3] + eb.w;

    int   idxs[TOPK];
    float probs[TOPK];
    float psum = 0.f;

    #pragma unroll
    for (int r = 0; r < TOPK; r++) {
        float bv = -INFINITY, bz = 0.f; int bidx = 1 << 30;
        #pragma unroll
        for (int i = 0; i < 4; i++)
            if (sel[i] > bv) { bv = sel[i]; bz = z[i]; bidx = l * 4 + i; }
        #pragma unroll
        for (int m = 1; m < 16; m <<= 1) {       // xor<16 stays in-group
            float ov = __shfl_xor(bv, m);
            float oz = __shfl_xor(bz, m);
            int   oi = __shfl_xor(bidx, m);
            if (ov > bv || (ov == bv && oi < bidx)) { bv = ov; bz = oz; bidx = oi; }
        }
        idxs[r] = bidx;
        float p = 1.f / (1.f + expf(-bz));
        probs[r] = p; psum += p;
        if ((bidx >> 2) == l) sel[bidx & 3] = -INFINITY;   // mark used
    }

    float inv = 1.f / psum;
    if (l < TOPK) {
        out[(size_t)t * TOPK + l] = (float)idxs[l];
        out[(size_t)NTOK * TOPK + (size_t)t * TOPK + l] = probs[l] * inv;
        if (mask[t] != 0) atomicAdd(&cnt[idxs[l]], 1u);
    }
    __syncthreads();
    if (tid < NEXP)
        blockcnt[(size_t)blockIdx.x * NEXP + tid] = (float)cnt[tid];
}

// ============================================================================
// Kernel 4: tree-sum per-block counts -> maxvio. One block, 256 threads.
// Thread (c = tid>>6, e = tid&63) sums blocks c*256..c*256+255 (coalesced
// across lanes), then 4-way combine + wave reduce.
// ============================================================================
__global__ __launch_bounds__(256) void finalize_kernel(
    const float* __restrict__ blockcnt, float* __restrict__ out)
{
    __shared__ float ps[4][NEXP];
    const int t = threadIdx.x;
    const int e = t & 63, c = t >> 6;
    float s = 0.f;
    #pragma unroll 8
    for (int b = 0; b < RBLK / 4; b++)
        s += blockcnt[(size_t)(c * (RBLK / 4) + b) * NEXP + e];
    ps[c][e] = s;
    __syncthreads();
    if (t < 64) {
        float tot = ps[0][t] + ps[1][t] + ps[2][t] + ps[3][t];
        float mx = tot, sm = tot;
        #pragma unroll
        for (int o = 32; o > 0; o >>= 1) {
            mx = fmaxf(mx, __shfl_down(mx, o));
            sm += __shfl_down(sm, o);
        }
        if (t == 0) {
            float avg = sm / (float)NEXP;
            out[2 * NTOK * TOPK] = (mx - avg) / (avg + 1e-5f);
        }
    }
}

// ============================================================================
// Fallback for tiny workspace: R1 fused kernel (known-correct) + atomic counts.
// ============================================================================
__global__ __launch_bounds__(256) void fused_fallback_kernel(
    const float* __restrict__ x, const int* __restrict__ mask,
    const float* __restrict__ W, const float* __restrict__ gbias,
    const float* __restrict__ ebias, float* __restrict__ out,
    unsigned int* __restrict__ counts)
{
    __shared__ float As[64][36];
    __shared__ float Bs[64][36];
    __shared__ float Lg[64][NEXP + 1];
    __shared__ float s_gb[NEXP], s_eb[NEXP];
    __shared__ unsigned int s_cnt[NEXP];
    const int tid = threadIdx.x;
    const int tx = tid & 15, ty = tid >> 4;
    const int m0 = blockIdx.x * 64;
    if (tid < NEXP) { s_gb[tid] = gbias[tid]; s_eb[tid] = ebias[tid]; s_cnt[tid] = 0u; }
    float acc[4][4] = {};
    for (int kb = 0; kb < CDIM; kb += 32) {
        __syncthreads();
        #pragma unroll
        for (int p = 0; p < 2; p++) {
            int lin = tid + p * 256; int m = lin >> 3; int c4 = (lin & 7) << 2;
            *(float4*)&As[m][c4] = *(const float4*)&x[(size_t)(m0 + m) * CDIM + kb + c4];
            *(float4*)&Bs[m][c4] = *(const float4*)&W[(size_t)m * CDIM + kb + c4];
        }
        __syncthreads();
        #pragma unroll
        for (int k4 = 0; k4 < 32; k4 += 4) {
            float4 a[4], b[4];
            #pragma unroll
            for (int i = 0; i < 4; i++) a[i] = *(const float4*)&As[ty * 4 + i][k4];
            #pragma unroll
            for (int j = 0; j < 4; j++) b[j] = *(const float4*)&Bs[tx * 4 + j][k4];
            #pragma unroll
            for (int i = 0; i < 4; i++)
                #pragma unroll
                for (int j = 0; j < 4; j++)
                    acc[i][j] += a[i].x * b[j].x + a[i].y * b[j].y
                               + a[i].z * b[j].z + a[i].w * b[j].w;
        }
    }
    __syncthreads();
    #pragma unroll
    for (int i = 0; i < 4; i++)
        #pragma unroll
        for (int j = 0; j < 4; j++)
            Lg[ty * 4 + i][tx * 4 + j] = acc[i][j] + s_gb[tx * 4 + j];
    __syncthreads();
    if (tid < 64) {
        const int g = m0 + tid;
        unsigned long long used = 0ull;
        int idxs[TOPK]; float probs[TOPK]; float psum = 0.f;
        #pragma unroll
        for (int k = 0; k < TOPK; k++) {
            float best = -INFINITY; int bi = 0;
            for (int n = 0; n < NEXP; n++) {
                if ((used >> n) & 1ull) continue;
                float vv = Lg[tid][n] + s_eb[n];
                if (vv > best) { best = vv; bi = n; }
            }
            used |= (1ull << bi);
            idxs[k] = bi;
            float p = 1.f / (1.f + expf(-Lg[tid][bi]));
            probs[k] = p; psum += p;
        }
        float inv = 1.f / psum;
        #pragma unroll
        for (int k = 0; k < TOPK; k++) {
            out[(size_t)g * TOPK + k] = (float)idxs[k];
            out[(size_t)NTOK * TOPK + (size_t)g * TOPK + k] = probs[k] * inv;
        }
        if (mask[g] != 0)
            #pragma unroll
            for (int k = 0; k < TOPK; k++) atomicAdd(&s_cnt[idxs[k]], 1u);
    }
    __syncthreads();
    if (tid < NEXP && s_cnt[tid] != 0u) atomicAdd(&counts[tid], s_cnt[tid]);
}

__global__ void finalize_atomic_kernel(const unsigned int* __restrict__ counts,
                                       float* __restrict__ out)
{
    const int t = threadIdx.x;
    float c  = (float)counts[t];
    float mx = c, sm = c;
    #pragma unroll
    for (int o = 32; o > 0; o >>= 1) {
        mx = fmaxf(mx, __shfl_down(mx, o));
        sm += __shfl_down(sm, o);
    }
    if (t == 0) {
        float avg = sm / (float)NEXP;
        out[2 * NTOK * TOPK] = (mx - avg) / (avg + 1e-5f);
    }
}

extern "C" void kernel_launch(void* const* d_in, const int* in_sizes, int n_in,
                              void* d_out, int out_size, void* d_ws, size_t ws_size,
                              hipStream_t stream)
{
    const float* x     = (const float*)d_in[0];
    const int*   mask  = (const int*)  d_in[1];
    const float* W     = (const float*)d_in[2];
    const float* gbias = (const float*)d_in[3];
    const float* ebias = (const float*)d_in[4];
    float* out = (float*)d_out;

    // ws layout: [Wh 256KB][Wl 256KB][blockcnt 256KB][part 16MB]
    const size_t whB  = (size_t)NEXP * CDIM * sizeof(_Float16);       // 256 KB
    const size_t bcB  = (size_t)RBLK * NEXP * sizeof(float);          // 256 KB
    const size_t ptB  = (size_t)KSPLIT * NTOK * NEXP * sizeof(float); // 16 MB
    const size_t need = 2 * whB + bcB + ptB;

    if (ws_size >= need) {
        _Float16* Wh = (_Float16*)d_ws;
        _Float16* Wl = (_Float16*)((char*)d_ws + whB);
        float* blockcnt = (float*)((char*)d_ws + 2 * whB);
        float* part = (float*)((char*)d_ws + 2 * whB + bcB);

        pack_w16_kernel<<<64, 256, 0, stream>>>(W, Wh, Wl);
        gemm_f16split_kernel<<<256 * KSPLIT, 256, 0, stream>>>(x, Wh, Wl, part);
        reduce_topk_kernel<<<RBLK, 256, 0, stream>>>(part, mask, gbias, ebias, out, blockcnt);
        finalize_kernel<<<1, 256, 0, stream>>>(blockcnt, out);
        return;
    }

    // Fallback: fused fp32 kernel + global-atomic counts
    unsigned int* counts = (unsigned int*)d_ws;
    hipMemsetAsync(d_ws, 0, NEXP * sizeof(unsigned int), stream);
    fused_fallback_kernel<<<NTOK / 64, 256, 0, stream>>>(x, mask, W, gbias, ebias, out, counts);
    finalize_atomic_kernel<<<1, 64, 0, stream>>>(counts, out);
}